// Round 13
// baseline (2587.911 us; speedup 1.0000x reference)
//
#include <hip/hip_runtime.h>

// Furthest Point Sampling, B=8, C=3, N=65536, NUM_POINTS=1024.
//
// R13 = R12's proven protocol + POLLER/SCANNER WAVE SPECIALIZATION.
//
// Evidence R3..R12: every single-line IC exchange lands 1.63-1.82ms; additive
// models under-predict by ~1500cy. The untouched cost: the poller wave must
// finish its own scan + wave reduce + barrier + block reduce before it issues
// its FIRST poll load (~600-800cy of detection delay), and straggler max over
// 64 waves compounds. Fix:
//  - 320-thread blocks: waves 0-3 scan (16 reg-resident pts/thread); wave 4 is
//    a DEDICATED POLLER that never scans -- it spins on the slot line
//    continuously, so detection == last publish's IC visibility, fully
//    overlapped with the local scan.
//  - Publish without barrier: each scan wave's lane 0 stores its key to LDS
//    then ACQ_REL fetch_adds a MONOTONIC LDS counter (values 4(it-1)..4it-1;
//    no reset -> no reuse hazard; 4*1023 < 2^32). The wave that draws 4it-1
//    reduces the 4 keys and fires the single 8B agent-scope slot store.
//    ZERO __syncthreads in the main loop.
//  - Poller keeps the candidate-coords prefetch (lanes 0-15, scattered clean
//    lines), DPP-reduces the 16 slots, release-publishes (wi|it) + coords via
//    LDS mailbox/s_q; scan waves acquire-spin. s_q single-buffer is safe: the
//    poller reaches it+1 only after this block's own publish of it+1, which
//    requires its scan waves to have consumed s_q(it).
//  - Kept invariants: one 8B publish per block, ONE 128B polled line, tagged
//    depth-16 regions (0xAA poison tag 0xAAAA never matches it<1024 -> no
//    memset), bit-exact math, smaller-index tie-break.
//
// Key packing (idx < 65536): dist_bits(32) | (0xFFFF - idx)(16) | it(16).
// Max key = max dist, tie -> smaller index == jnp.argmax first-occurrence.
// Winning slice = wi >> 12 (block owns [slice*4096, slice*4096+4096)).
// Distance math: __fmul_rn/__fadd_rn (no FMA contraction) to bit-match numpy.

namespace {

constexpr int kB = 8;
constexpr int kN = 65536;
constexpr int kNP = 1024;
constexpr int kPB = 16;                       // blocks (slices) per batch
constexpr int kScanWaves = 4;
constexpr int kScanThreads = kScanWaves * 64;  // 256
constexpr int kThreads = kScanThreads + 64;    // +1 poller wave = 320
constexpr int kPPT = kN / (kPB * kScanThreads);  // 16 points per thread
constexpr int kGrp = kPPT / 4;                   // 4 float4 groups
constexpr int kRgn = 16;                         // region reuse depth (skew < 2)

__device__ __forceinline__ unsigned long long u64max(unsigned long long a,
                                                     unsigned long long b) {
  return a > b ? a : b;
}

template <int CTRL>
__device__ __forceinline__ unsigned long long dpp_u64_zero(unsigned long long v) {
  const unsigned lo =
      (unsigned)__builtin_amdgcn_update_dpp(0, (int)(unsigned)v, CTRL, 0xf, 0xf, false);
  const unsigned hi =
      (unsigned)__builtin_amdgcn_update_dpp(0, (int)(unsigned)(v >> 32), CTRL, 0xf, 0xf, false);
  return ((unsigned long long)hi << 32) | lo;
}

// 64-lane max via DPP (keys > 0 -> old=0 is an identity), broadcast lane 63.
__device__ __forceinline__ unsigned long long wave_max_u64(unsigned long long v) {
  v = u64max(v, dpp_u64_zero<0x111>(v));  // row_shr:1
  v = u64max(v, dpp_u64_zero<0x112>(v));  // row_shr:2
  v = u64max(v, dpp_u64_zero<0x114>(v));  // row_shr:4
  v = u64max(v, dpp_u64_zero<0x118>(v));  // row_shr:8
  v = u64max(v, dpp_u64_zero<0x142>(v));  // row_bcast:15
  v = u64max(v, dpp_u64_zero<0x143>(v));  // row_bcast:31
  const unsigned lo = (unsigned)__builtin_amdgcn_readlane((int)(unsigned)v, 63);
  const unsigned hi = (unsigned)__builtin_amdgcn_readlane((int)(unsigned)(v >> 32), 63);
  return ((unsigned long long)hi << 32) | lo;
}

__global__ __launch_bounds__(kThreads) void fps_kernel(const float* __restrict__ pts,
                                                       float* __restrict__ out,
                                                       unsigned long long* __restrict__ slots) {
  const int batch = blockIdx.x & 7;
  const int slice = blockIdx.x >> 3;  // 0..15
  const int tid = threadIdx.x;
  const int lane = tid & 63;
  const int wave = tid >> 6;  // 0..3 scan, 4 poller

  const float* __restrict__ xb = pts + (size_t)batch * 3 * kN;
  const float* __restrict__ yb = xb + kN;
  const float* __restrict__ zb = xb + 2 * kN;

  __shared__ unsigned long long s_wkey[kScanWaves];
  __shared__ unsigned s_cnt;     // monotonic publish counter (4 per iteration)
  __shared__ float s_q[3];       // winner coords (this iteration)
  __shared__ unsigned s_win[2];  // parity mailbox: (wi << 16) | it
  __shared__ int s_hist[kNP];

  if (tid == 0) {
    s_cnt = 0;
    s_win[0] = 0xFFFFFFFFu;  // tag 0xFFFF never matches it < 1024
    s_win[1] = 0xFFFFFFFFu;
  }
  __syncthreads();  // init barrier (outside the main loop)

  unsigned long long* const sb = slots + (size_t)batch * kRgn * kPB;

  if (wave < kScanWaves) {
    // ================= SCAN WAVES =================
    // Register-resident coords: block owns [slice*4096, slice*4096+4096).
    const int sbase = slice * (kScanThreads * kPPT);
    const int base0 = sbase + tid * 4;
    float px[kPPT], py[kPPT], pz[kPPT], dist[kPPT];
#pragma unroll
    for (int g = 0; g < kGrp; ++g) {
      const int base = base0 + g * (kScanThreads * 4);
      const float4 vx = *reinterpret_cast<const float4*>(xb + base);
      const float4 vy = *reinterpret_cast<const float4*>(yb + base);
      const float4 vz = *reinterpret_cast<const float4*>(zb + base);
      px[g * 4 + 0] = vx.x; px[g * 4 + 1] = vx.y; px[g * 4 + 2] = vx.z; px[g * 4 + 3] = vx.w;
      py[g * 4 + 0] = vy.x; py[g * 4 + 1] = vy.y; py[g * 4 + 2] = vy.z; py[g * 4 + 3] = vy.w;
      pz[g * 4 + 0] = vz.x; pz[g * 4 + 1] = vz.y; pz[g * 4 + 2] = vz.z; pz[g * 4 + 3] = vz.w;
    }
#pragma unroll
    for (int k = 0; k < kPPT; ++k) dist[k] = 1e10f;

    // Seed: index 0 (uniform broadcast load, once).
    float qx = xb[0], qy = yb[0], qz = zb[0];

    for (int it = 1; it < kNP; ++it) {
      const unsigned tag = (unsigned)it;

      // --- update dists + per-thread argmax (ascending index, strict '>') ---
      float bd = -1.0f;
      int bi = 0;
#pragma unroll
      for (int g = 0; g < kGrp; ++g) {
#pragma unroll
        for (int j = 0; j < 4; ++j) {
          const int k = g * 4 + j;
          const float dx = px[k] - qx;
          const float dy = py[k] - qy;
          const float dz = pz[k] - qz;
          const float ss =
              __fadd_rn(__fadd_rn(__fmul_rn(dx, dx), __fmul_rn(dy, dy)), __fmul_rn(dz, dz));
          const float nd = fminf(dist[k], ss);
          dist[k] = nd;
          if (nd > bd) {
            bd = nd;
            bi = base0 + g * (kScanThreads * 4) + j;
          }
        }
      }

      // key: dist(32) | (0xFFFF - idx)(16) | it(16).
      unsigned long long key = ((unsigned long long)__float_as_uint(bd) << 32) |
                               ((unsigned long long)(0xFFFFu - (unsigned)bi) << 16) |
                               (unsigned long long)tag;

      // --- DPP wave max; lane 0: post key, count, maybe publish ---
      key = wave_max_u64(key);
      if (lane == 0) {
        s_wkey[wave] = key;
        // ACQ_REL: releases our s_wkey store; acquires all earlier posters'.
        const unsigned n =
            __hip_atomic_fetch_add(&s_cnt, 1u, __ATOMIC_ACQ_REL, __HIP_MEMORY_SCOPE_WORKGROUP);
        if (n == 4u * (unsigned)it - 1u) {
          // Last finisher: reduce the 4 wave keys, fire the slot store.
          unsigned long long bk = s_wkey[0];
          bk = u64max(bk, s_wkey[1]);
          bk = u64max(bk, s_wkey[2]);
          bk = u64max(bk, s_wkey[3]);
          __hip_atomic_store(sb + (size_t)(it & (kRgn - 1)) * kPB + slice, bk,
                             __ATOMIC_RELAXED, __HIP_MEMORY_SCOPE_AGENT);
        }
      }

      // --- acquire-spin on the mailbox; coords from LDS ---
      unsigned v;
      do {
        v = __hip_atomic_load(&s_win[it & 1], __ATOMIC_ACQUIRE, __HIP_MEMORY_SCOPE_WORKGROUP);
      } while ((v & 0xFFFFu) != tag);
      qx = s_q[0];
      qy = s_q[1];
      qz = s_q[2];
    }
  } else {
    // ================= POLLER WAVE (never scans) =================
    for (int it = 1; it < kNP; ++it) {
      const unsigned tag = (unsigned)it;
      const unsigned long long* const myslot =
          sb + (size_t)(it & (kRgn - 1)) * kPB + (lane & (kPB - 1));

      float cx = 0.f, cy = 0.f, cz = 0.f;
      bool have = false;
      unsigned long long w;
      for (;;) {
        const unsigned long long a =
            __hip_atomic_load(myslot, __ATOMIC_RELAXED, __HIP_MEMORY_SCOPE_AGENT);
        const bool va = (unsigned)(a & 0xFFFFull) == tag;
        // Prefetch this slot's candidate coords the moment it turns valid
        // (lanes 0..15; scattered clean lines, off the hot slot line).
        if ((lane < kPB) && va && !have) {
          const int ci = (int)(0xFFFFu - ((unsigned)(a >> 16) & 0xFFFFu));
          cx = xb[ci];
          cy = yb[ci];
          cz = zb[ci];
          have = true;
        }
        if (__all(va)) {
          w = a;
          break;
        }
      }

      // --- DPP max over 16 slots (4x replicated lanes) ---
      const unsigned long long mx = wave_max_u64(w);
      const int wi = (int)(0xFFFFu - ((unsigned)(mx >> 16) & 0xFFFFu));
      const int winslot = wi >> 12;  // slice that owns index wi
      const float qx = __shfl(cx, winslot, 64);
      const float qy = __shfl(cy, winslot, 64);
      const float qz = __shfl(cz, winslot, 64);
      if (lane == 0) {
        s_hist[it] = wi;
        s_q[0] = qx;
        s_q[1] = qy;
        s_q[2] = qz;
        // RELEASE orders the s_q/s_hist stores before the mailbox flag.
        __hip_atomic_store(&s_win[it & 1], ((unsigned)wi << 16) | tag, __ATOMIC_RELEASE,
                           __HIP_MEMORY_SCOPE_WORKGROUP);
      }
    }
  }

  __syncthreads();  // s_hist complete and visible block-wide

  // --- gather: out[b][c][j] = points[b][c][idx_j]; slice-0 block per batch ---
  if (slice == 0) {
    float* __restrict__ ob = out + (size_t)batch * 3 * kNP;
    for (int j = tid; j < kNP; j += kThreads) {
      const int id = (j == 0) ? 0 : s_hist[j];
      ob[j] = xb[id];
      ob[kNP + j] = yb[id];
      ob[2 * kNP + j] = zb[id];
    }
  }
}

}  // namespace

extern "C" void kernel_launch(void* const* d_in, const int* in_sizes, int n_in,
                              void* d_out, int out_size, void* d_ws, size_t ws_size,
                              hipStream_t stream) {
  (void)in_sizes;
  (void)n_in;
  (void)out_size;
  (void)ws_size;
  const float* pts = (const float*)d_in[0];
  float* out = (float*)d_out;
  // 8 batches x 16 regions x 16 slots x 8B = 16 KB of d_ws. Tag-validated
  // (0xAA poison -> tag 0xAAAA never equals it < 1024) => NO memset; region
  // reuse depth 16 >> max block skew (< 2 iterations).
  unsigned long long* slots = (unsigned long long*)d_ws;
  fps_kernel<<<dim3(kB * kPB), dim3(kThreads), 0, stream>>>(pts, out, slots);
}

// Round 14
// 1720.173 us; speedup vs baseline: 1.5044x; 1.5044x over previous
//
#include <hip/hip_runtime.h>

// Furthest Point Sampling, B=8, C=3, N=65536, NUM_POINTS=1024.
//
// R14 = R12 (best protocol family) + POLL BACKOFF.
//
// Evidence R5/R12/R13: poll-load pressure on the hot slot line correlates
// directly with iteration time (FETCH 3.6->6.5/7.0 MB == time 1.69->2.59 ms):
// readers holding the line in shared state delay the 16 writers' store
// visibility at the coherence point. Fix: after a failed poll round, s_sleep(1)
// (~64cy) before reloading -- halves steady-state reader pressure during the
// publish window, costs <=64cy detection quantization.
//
// Proven invariants kept (R3..R13): one 8B publish per block, ONE 128B polled
// line per batch-iteration, single poller wave that polls only after its own
// scan, candidate-coords prefetch, DPP reductions, tagged depth-16 slot
// regions (0xAA poison tag 0xAAAA never matches it < 1024 -> no memset),
// one barrier per iteration, LDS mailbox fanout.
//
// Key packing (idx < 65536): dist_bits(32) | (0xFFFF - idx)(16) | it(16).
// Max key = max dist, tie -> smaller index == jnp.argmax first-occurrence
// (dist >= 0 -> float bits monotone; same tag on all keys of an iteration).
// Winning slice = wi >> 12 (block owns [slice*4096, slice*4096+4096)).
// Distance math: __fmul_rn/__fadd_rn (no FMA contraction) to bit-match numpy.

namespace {

constexpr int kB = 8;
constexpr int kN = 65536;
constexpr int kNP = 1024;
constexpr int kPB = 16;                      // blocks (slices) per batch
constexpr int kThreads = 256;
constexpr int kPPT = kN / (kPB * kThreads);  // 16 points per thread
constexpr int kGrp = kPPT / 4;               // 4 float4 groups
constexpr int kWaves = kThreads / 64;        // 4
constexpr int kRgn = 16;                     // region reuse depth (skew < 2)

__device__ __forceinline__ unsigned long long u64max(unsigned long long a,
                                                     unsigned long long b) {
  return a > b ? a : b;
}

template <int CTRL>
__device__ __forceinline__ unsigned long long dpp_u64_zero(unsigned long long v) {
  const unsigned lo =
      (unsigned)__builtin_amdgcn_update_dpp(0, (int)(unsigned)v, CTRL, 0xf, 0xf, false);
  const unsigned hi =
      (unsigned)__builtin_amdgcn_update_dpp(0, (int)(unsigned)(v >> 32), CTRL, 0xf, 0xf, false);
  return ((unsigned long long)hi << 32) | lo;
}

// 64-lane max via DPP (keys > 0 -> old=0 is an identity), broadcast lane 63.
__device__ __forceinline__ unsigned long long wave_max_u64(unsigned long long v) {
  v = u64max(v, dpp_u64_zero<0x111>(v));  // row_shr:1
  v = u64max(v, dpp_u64_zero<0x112>(v));  // row_shr:2
  v = u64max(v, dpp_u64_zero<0x114>(v));  // row_shr:4
  v = u64max(v, dpp_u64_zero<0x118>(v));  // row_shr:8
  v = u64max(v, dpp_u64_zero<0x142>(v));  // row_bcast:15
  v = u64max(v, dpp_u64_zero<0x143>(v));  // row_bcast:31
  const unsigned lo = (unsigned)__builtin_amdgcn_readlane((int)(unsigned)v, 63);
  const unsigned hi = (unsigned)__builtin_amdgcn_readlane((int)(unsigned)(v >> 32), 63);
  return ((unsigned long long)hi << 32) | lo;
}

__global__ __launch_bounds__(kThreads) void fps_kernel(const float* __restrict__ pts,
                                                       float* __restrict__ out,
                                                       unsigned long long* __restrict__ slots) {
  const int batch = blockIdx.x & 7;
  const int slice = blockIdx.x >> 3;  // 0..15
  const int tid = threadIdx.x;
  const int lane = tid & 63;
  const int wave = tid >> 6;

  const float* __restrict__ xb = pts + (size_t)batch * 3 * kN;
  const float* __restrict__ yb = xb + kN;
  const float* __restrict__ zb = xb + 2 * kN;

  __shared__ unsigned long long s_wkey[kWaves];
  __shared__ float s_q[3];       // winner coords (this iteration)
  __shared__ unsigned s_win[2];  // parity mailbox: (wi << 16) | it
  __shared__ int s_hist[kNP];

  if (tid == 0) {
    s_win[0] = 0xFFFFFFFFu;  // tag 0xFFFF never matches it < 1024
    s_win[1] = 0xFFFFFFFFu;
  }

  // Register-resident coords: block owns [slice*4096, slice*4096+4096).
  const int sbase = slice * (kThreads * kPPT);
  const int base0 = sbase + tid * 4;
  float px[kPPT], py[kPPT], pz[kPPT], dist[kPPT];
#pragma unroll
  for (int g = 0; g < kGrp; ++g) {
    const int base = base0 + g * (kThreads * 4);
    const float4 vx = *reinterpret_cast<const float4*>(xb + base);
    const float4 vy = *reinterpret_cast<const float4*>(yb + base);
    const float4 vz = *reinterpret_cast<const float4*>(zb + base);
    px[g * 4 + 0] = vx.x; px[g * 4 + 1] = vx.y; px[g * 4 + 2] = vx.z; px[g * 4 + 3] = vx.w;
    py[g * 4 + 0] = vy.x; py[g * 4 + 1] = vy.y; py[g * 4 + 2] = vy.z; py[g * 4 + 3] = vy.w;
    pz[g * 4 + 0] = vz.x; pz[g * 4 + 1] = vz.y; pz[g * 4 + 2] = vz.z; pz[g * 4 + 3] = vz.w;
  }
#pragma unroll
  for (int k = 0; k < kPPT; ++k) dist[k] = 1e10f;

  // Seed: index 0 (uniform broadcast load, once).
  float qx = xb[0], qy = yb[0], qz = zb[0];

  unsigned long long* const sb = slots + (size_t)batch * kRgn * kPB;

  for (int it = 1; it < kNP; ++it) {
    const unsigned tag = (unsigned)it;

    // --- update dists + per-thread argmax (ascending index, strict '>') ---
    float bd = -1.0f;
    int bi = 0;
#pragma unroll
    for (int g = 0; g < kGrp; ++g) {
#pragma unroll
      for (int j = 0; j < 4; ++j) {
        const int k = g * 4 + j;
        const float dx = px[k] - qx;
        const float dy = py[k] - qy;
        const float dz = pz[k] - qz;
        const float ss =
            __fadd_rn(__fadd_rn(__fmul_rn(dx, dx), __fmul_rn(dy, dy)), __fmul_rn(dz, dz));
        const float nd = fminf(dist[k], ss);
        dist[k] = nd;
        if (nd > bd) {
          bd = nd;
          bi = base0 + g * (kThreads * 4) + j;
        }
      }
    }

    // key: dist(32) | (0xFFFF - idx)(16) | it(16)  -- tag self-validates slots.
    unsigned long long key = ((unsigned long long)__float_as_uint(bd) << 32) |
                             ((unsigned long long)(0xFFFFu - (unsigned)bi) << 16) |
                             (unsigned long long)tag;

    // --- DPP wave max ---
    key = wave_max_u64(key);
    if (lane == 0) s_wkey[wave] = key;
    __syncthreads();  // the only barrier in the iteration

    if (wave == 0) {
      // --- block max over 4 wave keys (DPP on replicated lanes) ---
      unsigned long long bk = s_wkey[lane & (kWaves - 1)];
      bk = wave_max_u64(bk);

      unsigned long long* const rgn = sb + (size_t)(it & (kRgn - 1)) * kPB;
      if (lane == 0) {
        __hip_atomic_store(rgn + slice, bk, __ATOMIC_RELAXED, __HIP_MEMORY_SCOPE_AGENT);
      }

      // --- poll with backoff + candidate-coords prefetch ---
      const unsigned long long* const myslot = rgn + (lane & (kPB - 1));
      float cx = 0.f, cy = 0.f, cz = 0.f;
      bool have = false;
      unsigned long long w;
      for (;;) {
        const unsigned long long a =
            __hip_atomic_load(myslot, __ATOMIC_RELAXED, __HIP_MEMORY_SCOPE_AGENT);
        const bool va = (unsigned)(a & 0xFFFFull) == tag;
        // Prefetch this slot's candidate coords the moment it turns valid
        // (lanes 0..15 only; scattered clean lines, off the hot slot line).
        if ((lane < kPB) && va && !have) {
          const int ci = (int)(0xFFFFu - ((unsigned)(a >> 16) & 0xFFFFu));
          cx = xb[ci];
          cy = yb[ci];
          cz = zb[ci];
          have = true;
        }
        if (__all(va)) {
          w = a;
          break;
        }
        // Backoff: halve reader pressure on the hot line while the remaining
        // publishes are landing (costs <=64cy detection quantization).
        __builtin_amdgcn_s_sleep(1);
      }

      // --- DPP max over 16 slots (4x replicated lanes) ---
      const unsigned long long mx = wave_max_u64(w);
      const int wi = (int)(0xFFFFu - ((unsigned)(mx >> 16) & 0xFFFFu));
      const int winslot = wi >> 12;  // slice that owns index wi
      // Winner coords from the prefetching lane (already in flight/registers).
      qx = __shfl(cx, winslot, 64);
      qy = __shfl(cy, winslot, 64);
      qz = __shfl(cz, winslot, 64);
      if (lane == 0) {
        s_hist[it] = wi;
        s_q[0] = qx;
        s_q[1] = qy;
        s_q[2] = qz;
        // RELEASE orders the s_q stores before the mailbox flag.
        __hip_atomic_store(&s_win[it & 1], ((unsigned)wi << 16) | tag, __ATOMIC_RELEASE,
                           __HIP_MEMORY_SCOPE_WORKGROUP);
      }
    } else {
      // --- waves 1-3: acquire-spin on the mailbox; coords from LDS ---
      unsigned v;
      do {
        v = __hip_atomic_load(&s_win[it & 1], __ATOMIC_ACQUIRE, __HIP_MEMORY_SCOPE_WORKGROUP);
      } while ((v & 0xFFFFu) != tag);
      qx = s_q[0];
      qy = s_q[1];
      qz = s_q[2];
    }
  }

  __syncthreads();  // s_hist complete and visible block-wide

  // --- gather: out[b][c][j] = points[b][c][idx_j]; slice-0 block per batch ---
  if (slice == 0) {
    float* __restrict__ ob = out + (size_t)batch * 3 * kNP;
    for (int j = tid; j < kNP; j += kThreads) {
      const int id = (j == 0) ? 0 : s_hist[j];
      ob[j] = xb[id];
      ob[kNP + j] = yb[id];
      ob[2 * kNP + j] = zb[id];
    }
  }
}

}  // namespace

extern "C" void kernel_launch(void* const* d_in, const int* in_sizes, int n_in,
                              void* d_out, int out_size, void* d_ws, size_t ws_size,
                              hipStream_t stream) {
  (void)in_sizes;
  (void)n_in;
  (void)out_size;
  (void)ws_size;
  const float* pts = (const float*)d_in[0];
  float* out = (float*)d_out;
  // 8 batches x 16 regions x 16 slots x 8B = 16 KB of d_ws. Tag-validated
  // (0xAA poison -> tag 0xAAAA never equals it < 1024) => NO memset; region
  // reuse depth 16 >> max block skew (< 2 iterations).
  unsigned long long* slots = (unsigned long long*)d_ws;
  fps_kernel<<<dim3(kB * kPB), dim3(kThreads), 0, stream>>>(pts, out, slots);
}